// Round 4
// baseline (688.067 us; speedup 1.0000x reference)
//
#include <hip/hip_runtime.h>
#include <hip/hip_bf16.h>
#include <string.h>

typedef _Float16 half8 __attribute__((ext_vector_type(8)));
typedef _Float16 half4 __attribute__((ext_vector_type(4)));
typedef float f32x4 __attribute__((ext_vector_type(4)));
typedef float f32x16 __attribute__((ext_vector_type(16)));

#define NTOK 4096
#define CDIM 256

#define GLD_LDS16(g, l) __builtin_amdgcn_global_load_lds( \
    (const __attribute__((address_space(1))) void*)(g), \
    (__attribute__((address_space(3))) void*)(l), 16, 0, 0)

static __device__ __forceinline__ unsigned pk16(float a, float b) {
    auto h = __builtin_amdgcn_cvt_pkrtz(a, b);   // 2 x f16 packed, rtz
    unsigned u;
    __builtin_memcpy(&u, &h, 4);
    return u;
}

// ---------------------------------------------------------------------------
// Kernel 1: projections (unchanged, known-good).
// Q,K token-major [bs][N][C] fp16; V channel-major [bs][C][N] fp16. bs=b*2+s.
// ---------------------------------------------------------------------------
__global__ __launch_bounds__(256, 2) void proj_kernel(
    const float* __restrict__ x1, const float* __restrict__ x2,
    const float* __restrict__ Wq, const float* __restrict__ bq,
    const float* __restrict__ Wk, const float* __restrict__ bk,
    const float* __restrict__ Wv, const float* __restrict__ bv,
    _Float16* __restrict__ Qh, _Float16* __restrict__ Kh,
    _Float16* __restrict__ Vt)
{
    __shared__ __align__(16) _Float16 Xl[64][264];
    __shared__ __align__(16) _Float16 Wl[64][264];
    __shared__ __align__(16) _Float16 Ol[64][68];

    const int t = threadIdx.x;
    const int lane = t & 63;
    const int w = t >> 6;
    const int bs = blockIdx.x >> 6;
    const int ntile = blockIdx.x & 63;
    const int n0 = ntile * 64;
    const int s = bs & 1, b = bs >> 1;

    const float* x = (s ? x2 : x1) + (size_t)b * CDIM * NTOK;

#pragma unroll
    for (int i = 0; i < 16; i++) {
        int id = t + 256 * i;
        int c = id >> 4, n4 = (id & 15) * 4;
        float4 v = *(const float4*)(x + (size_t)c * NTOK + n0 + n4);
        Xl[n4 + 0][c] = (_Float16)v.x;
        Xl[n4 + 1][c] = (_Float16)v.y;
        Xl[n4 + 2][c] = (_Float16)v.z;
        Xl[n4 + 3][c] = (_Float16)v.w;
    }

    for (int proj = 0; proj < 3; proj++) {
        const float* Wp = proj == 0 ? Wq : (proj == 1 ? Wk : Wv);
        const float* bp = proj == 0 ? bq : (proj == 1 ? bk : bv);
        for (int dt = 0; dt < 4; dt++) {
            const int d0 = dt * 64;
            __syncthreads();
#pragma unroll
            for (int i = 0; i < 16; i++) {
                int id = t + 256 * i;
                int d = id >> 6, c4 = (id & 63) * 4;
                float4 v = *(const float4*)(Wp + (size_t)(d0 + d) * CDIM + c4);
                half4 h = { (_Float16)v.x, (_Float16)v.y, (_Float16)v.z, (_Float16)v.w };
                *(half4*)&Wl[d][c4] = h;
            }
            __syncthreads();

            f32x4 acc[4];
            const f32x4 fz = {0.f, 0.f, 0.f, 0.f};
#pragma unroll
            for (int nt = 0; nt < 4; nt++) acc[nt] = fz;
#pragma unroll
            for (int cc = 0; cc < 8; cc++) {
                half8 wf = *(const half8*)&Wl[16 * w + (lane & 15)][cc * 32 + (lane >> 4) * 8];
#pragma unroll
                for (int nt = 0; nt < 4; nt++) {
                    half8 xf = *(const half8*)&Xl[nt * 16 + (lane & 15)][cc * 32 + (lane >> 4) * 8];
                    acc[nt] = __builtin_amdgcn_mfma_f32_16x16x32_f16(wf, xf, acc[nt], 0, 0, 0);
                }
            }
#pragma unroll
            for (int r = 0; r < 4; r++) {
                float bias = bp[d0 + 16 * w + (lane >> 4) * 4 + r];
#pragma unroll
                for (int nt = 0; nt < 4; nt++) {
                    _Float16 hv = (_Float16)(acc[nt][r] + bias);
                    if (proj < 2) Ol[nt * 16 + (lane & 15)][16 * w + (lane >> 4) * 4 + r] = hv;
                    else          Ol[16 * w + (lane >> 4) * 4 + r][nt * 16 + (lane & 15)] = hv;
                }
            }
            __syncthreads();
            _Float16* dst;
            size_t stride;
            if (proj == 0)      { dst = Qh + ((size_t)bs * NTOK + n0) * CDIM + d0; stride = CDIM; }
            else if (proj == 1) { dst = Kh + ((size_t)bs * NTOK + n0) * CDIM + d0; stride = CDIM; }
            else                { dst = Vt + ((size_t)bs * CDIM + d0) * NTOK + n0; stride = NTOK; }
#pragma unroll
            for (int i = 0; i < 4; i++) {
                int id = t + 256 * i;
                int row = id >> 4, c4 = (id & 15) * 4;
                *(half4*)(dst + (size_t)row * stride + c4) = *(const half4*)&Ol[row][c4];
            }
        }
    }
}

// ---------------------------------------------------------------------------
// Kernel 2: flash attention v3b — 32x32x16 MFMA, swapped QK^T (S^T in regs,
// softmax row fully in-lane), P->A-frag via cvt_pkrtz + permlane32_swap
// (FIXED direction: dst=A-pair, src=B-pair; word0=new_dst, word2=new_src),
// K double-buffered in LDS (conflict-free XOR swizzle, global_load_lds),
// V read directly from L2 (XCD-pinned, 4MB).
// Block = 4 waves x 32 q-rows = 128 rows; 256 blocks; LDS 64KB -> 2 blk/CU.
// ---------------------------------------------------------------------------
__global__ __launch_bounds__(256, 2) void flash_kernel(
    const _Float16* __restrict__ Qh, const _Float16* __restrict__ Kh,
    const _Float16* __restrict__ Vt, float* __restrict__ out)
{
    __shared__ __align__(16) char smem[65536];   // K dbuf 2x32KB; epilogue reuse

    const int t = threadIdx.x, lane = t & 63;
    const int w = t >> 6;
    const int l5 = lane & 31, hi = lane >> 5;
    const int bs = blockIdx.x & 7;               // XCD-affine (256 % 8 == 0)
    const int qt = blockIdx.x >> 3;
    const int n0 = qt * 128;
    const int s = bs & 1, b = bs >> 1;

    // Q B-frags: col n = w*32 + l5, k(c) = cc*16 + hi*8 + j
    half8 qf[16];
    {
        const _Float16* qp = Qh + ((size_t)bs * NTOK + n0 + w * 32 + l5) * CDIM + hi * 8;
#pragma unroll
        for (int cc = 0; cc < 16; cc++) qf[cc] = *(const half8*)(qp + cc * 16);
    }

    const int bsK = b * 2 + (s ^ 1);
    const uint4* const Ksrc = (const uint4*)(Kh + (size_t)bsK * NTOK * CDIM);
    const _Float16* const Vb = Vt + (size_t)bs * CDIM * NTOK;

    float m_run = -1e30f, l_run = 0.f;
    f32x16 Oacc[8];
    const f32x16 FZ16 = {0,0,0,0,0,0,0,0,0,0,0,0,0,0,0,0};
#pragma unroll
    for (int ct = 0; ct < 8; ct++) Oacc[ct] = FZ16;

    // stage K tile [64 m][256 c] (row = 32 chunks of 16B), chunk pre-XORed by m&31
    auto stageK = [&](int buf, int kt) {
        char* kdst = smem + buf * 32768 + w * 8192;
#pragma unroll
        for (int i = 0; i < 8; i++) {
            int id = w * 512 + i * 64 + lane;
            int m = id >> 5, pos = id & 31;
            GLD_LDS16(Ksrc + (size_t)(kt * 64 + m) * 32 + (pos ^ (m & 31)), kdst + i * 1024);
        }
    };

    stageK(0, 0);
    __syncthreads();

    for (int kt = 0; kt < 64; kt++) {
        const int cur = kt & 1;
        if (kt < 63) stageK(cur ^ 1, kt + 1);
        const char* Kb = smem + cur * 32768;
        const int m0 = kt * 64;

        // ---- S^T = K Q^T : D col = q-row n (=l5), rows = m tokens
        f32x16 sf[2];
        sf[0] = FZ16; sf[1] = FZ16;
#pragma unroll
        for (int cc = 0; cc < 16; cc++) {
#pragma unroll
            for (int mt = 0; mt < 2; mt++) {
                int m = mt * 32 + l5;
                half8 kf = *(const half8*)(Kb + m * 512 + ((((cc << 1) | hi) ^ (m & 31)) << 4));
                sf[mt] = __builtin_amdgcn_mfma_f32_32x32x16_f16(kf, qf[cc], sf[mt], 0, 0, 0);
            }
        }

        // ---- online softmax, row n = l5 fully in-lane (+ partner half)
        float pm = sf[0][0];
#pragma unroll
        for (int mt = 0; mt < 2; mt++)
#pragma unroll
            for (int r = 0; r < 16; r++) pm = fmaxf(pm, sf[mt][r]);
        pm = fmaxf(pm, __shfl_xor(pm, 32));

        if (__any(pm > m_run + 8.0f)) {        // defer-max: rescale only on growth
            float nm = fmaxf(m_run, pm);
            float sc = __expf(m_run - nm);
            m_run = nm;
            l_run *= sc;
#pragma unroll
            for (int reg = 0; reg < 16; reg++) {
                float sr = __shfl(sc, (reg & 3) + 8 * (reg >> 2) + 4 * hi);
#pragma unroll
                for (int ct = 0; ct < 8; ct++) Oacc[ct][reg] *= sr;
            }
        }

        float lsum = 0.f;
#pragma unroll
        for (int mt = 0; mt < 2; mt++)
#pragma unroll
            for (int r = 0; r < 16; r++) {
                float p = __expf(sf[mt][r] - m_run);
                sf[mt][r] = p;
                lsum += p;
            }
        lsum += __shfl_xor(lsum, 32);
        l_run += lsum;

        // ---- P -> A-frags in-register: 16 cvt_pk + 8 permlane32_swap.
        // Need word j pairs: hi=0: {m0+1, m2+3, m4+5, m6+7}; hi=1: {m8+9,...}.
        // swap(dst=A, src=B): new_dst = (A_low | B_low-of-partner),
        //                     new_src = (A_high-of-partner | B_high).
        uint4 paw[4];
#pragma unroll
        for (int kc = 0; kc < 4; kc++) {
            const int mt = kc >> 1;
            const int qe = (kc & 1) * 8;
            unsigned A01 = pk16(sf[mt][qe + 0], sf[mt][qe + 1]);
            unsigned A23 = pk16(sf[mt][qe + 2], sf[mt][qe + 3]);
            unsigned B01 = pk16(sf[mt][qe + 4], sf[mt][qe + 5]);
            unsigned B23 = pk16(sf[mt][qe + 6], sf[mt][qe + 7]);
            unsigned d0 = A01, s0 = B01;
            asm volatile("v_permlane32_swap_b32 %0, %1" : "+v"(d0), "+v"(s0));
            unsigned d1 = A23, s1 = B23;
            asm volatile("v_permlane32_swap_b32 %0, %1" : "+v"(d1), "+v"(s1));
            paw[kc].x = d0; paw[kc].y = d1; paw[kc].z = s0; paw[kc].w = s1;
        }

        // ---- O += P V : V B-frags straight from global (L2-resident)
#pragma unroll
        for (int kc = 0; kc < 4; kc++) {
            half8 pa;
            __builtin_memcpy(&pa, &paw[kc], 16);
            const _Float16* vrow = Vb + m0 + kc * 16 + hi * 8;
#pragma unroll
            for (int ct = 0; ct < 8; ct++) {
                int c = ct * 32 + l5;
                half8 vf = *(const half8*)(vrow + (size_t)c * NTOK);
                Oacc[ct] = __builtin_amdgcn_mfma_f32_32x32x16_f16(pa, vf, Oacc[ct], 0, 0, 0);
            }
        }

        __syncthreads();   // all waves done with Kb[cur]; prefetch into cur^1 drained
    }

    // ---- epilogue: normalize, transpose via LDS (2 halves), coalesced store
    float inv = 1.0f / l_run;
    float invr[16];
#pragma unroll
    for (int reg = 0; reg < 16; reg++)
        invr[reg] = __shfl(inv, (reg & 3) + 8 * (reg >> 2) + 4 * hi);

    float* obase = out + (size_t)(s * 4 + b) * CDIM * NTOK + n0;
    char* const Olp = smem;   // [128 c][128 n] f32, n-chunk ^= (c&7)
#pragma unroll
    for (int h = 0; h < 2; h++) {
        if (h) __syncthreads();
#pragma unroll
        for (int ct4 = 0; ct4 < 4; ct4++) {
            int ct = h * 4 + ct4;
            int cl = ct4 * 32 + l5;
#pragma unroll
            for (int reg = 0; reg < 16; reg++) {
                int n = w * 32 + (reg & 3) + 8 * (reg >> 2) + 4 * hi;
                int byteoff = cl * 512 + n * 4;
                *(float*)(Olp + (byteoff ^ ((cl & 7) << 4))) = Oacc[ct][reg] * invr[reg];
            }
        }
        __syncthreads();
#pragma unroll
        for (int i = 0; i < 16; i++) {
            int id = t + 256 * i;
            int c = id >> 5, nc = id & 31;
            f32x4 v = *(const f32x4*)(Olp + c * 512 + (((nc ^ (c & 7))) << 4));
            *(f32x4*)(obase + (size_t)(h * 128 + c) * NTOK + nc * 4) = v;
        }
    }
}

// ---------------------------------------------------------------------------
extern "C" void kernel_launch(void* const* d_in, const int* in_sizes, int n_in,
                              void* d_out, int out_size, void* d_ws, size_t ws_size,
                              hipStream_t stream) {
    const float* x1 = (const float*)d_in[0];
    const float* x2 = (const float*)d_in[1];
    const float* Wq = (const float*)d_in[2];
    const float* bq = (const float*)d_in[3];
    const float* Wk = (const float*)d_in[4];
    const float* bk = (const float*)d_in[5];
    const float* Wv = (const float*)d_in[6];
    const float* bv = (const float*)d_in[7];

    _Float16* Qh = (_Float16*)d_ws;
    _Float16* Kh = Qh + (size_t)8 * NTOK * CDIM;
    _Float16* Vt = Kh + (size_t)8 * NTOK * CDIM;

    proj_kernel<<<dim3(512), dim3(256), 0, stream>>>(x1, x2, Wq, bq, Wk, bk, Wv, bv, Qh, Kh, Vt);
    flash_kernel<<<dim3(256), dim3(256), 0, stream>>>(Qh, Kh, Vt, (float*)d_out);
}

// Round 5
// 308.019 us; speedup vs baseline: 2.2338x; 2.2338x over previous
//
#include <hip/hip_runtime.h>
#include <hip/hip_bf16.h>
#include <string.h>

typedef _Float16 half8 __attribute__((ext_vector_type(8)));
typedef _Float16 half4 __attribute__((ext_vector_type(4)));
typedef float f32x4 __attribute__((ext_vector_type(4)));
typedef float f32x16 __attribute__((ext_vector_type(16)));

#define NTOK 4096
#define CDIM 256

#define GLD_LDS16(g, l) __builtin_amdgcn_global_load_lds( \
    (const __attribute__((address_space(1))) void*)(g), \
    (__attribute__((address_space(3))) void*)(l), 16, 0, 0)

static __device__ __forceinline__ unsigned pk16(float a, float b) {
    auto h = __builtin_amdgcn_cvt_pkrtz(a, b);   // 2 x f16 packed, rtz
    unsigned u;
    __builtin_memcpy(&u, &h, 4);
    return u;
}

// ---------------------------------------------------------------------------
// Kernel 1: projections (unchanged, known-good).
// Q,K token-major [bs][N][C] fp16; V channel-major [bs][C][N] fp16. bs=b*2+s.
// ---------------------------------------------------------------------------
__global__ __launch_bounds__(256, 2) void proj_kernel(
    const float* __restrict__ x1, const float* __restrict__ x2,
    const float* __restrict__ Wq, const float* __restrict__ bq,
    const float* __restrict__ Wk, const float* __restrict__ bk,
    const float* __restrict__ Wv, const float* __restrict__ bv,
    _Float16* __restrict__ Qh, _Float16* __restrict__ Kh,
    _Float16* __restrict__ Vt)
{
    __shared__ __align__(16) _Float16 Xl[64][264];
    __shared__ __align__(16) _Float16 Wl[64][264];
    __shared__ __align__(16) _Float16 Ol[64][68];

    const int t = threadIdx.x;
    const int lane = t & 63;
    const int w = t >> 6;
    const int bs = blockIdx.x >> 6;
    const int ntile = blockIdx.x & 63;
    const int n0 = ntile * 64;
    const int s = bs & 1, b = bs >> 1;

    const float* x = (s ? x2 : x1) + (size_t)b * CDIM * NTOK;

#pragma unroll
    for (int i = 0; i < 16; i++) {
        int id = t + 256 * i;
        int c = id >> 4, n4 = (id & 15) * 4;
        float4 v = *(const float4*)(x + (size_t)c * NTOK + n0 + n4);
        Xl[n4 + 0][c] = (_Float16)v.x;
        Xl[n4 + 1][c] = (_Float16)v.y;
        Xl[n4 + 2][c] = (_Float16)v.z;
        Xl[n4 + 3][c] = (_Float16)v.w;
    }

    for (int proj = 0; proj < 3; proj++) {
        const float* Wp = proj == 0 ? Wq : (proj == 1 ? Wk : Wv);
        const float* bp = proj == 0 ? bq : (proj == 1 ? bk : bv);
        for (int dt = 0; dt < 4; dt++) {
            const int d0 = dt * 64;
            __syncthreads();
#pragma unroll
            for (int i = 0; i < 16; i++) {
                int id = t + 256 * i;
                int d = id >> 6, c4 = (id & 63) * 4;
                float4 v = *(const float4*)(Wp + (size_t)(d0 + d) * CDIM + c4);
                half4 h = { (_Float16)v.x, (_Float16)v.y, (_Float16)v.z, (_Float16)v.w };
                *(half4*)&Wl[d][c4] = h;
            }
            __syncthreads();

            f32x4 acc[4];
            const f32x4 fz = {0.f, 0.f, 0.f, 0.f};
#pragma unroll
            for (int nt = 0; nt < 4; nt++) acc[nt] = fz;
#pragma unroll
            for (int cc = 0; cc < 8; cc++) {
                half8 wf = *(const half8*)&Wl[16 * w + (lane & 15)][cc * 32 + (lane >> 4) * 8];
#pragma unroll
                for (int nt = 0; nt < 4; nt++) {
                    half8 xf = *(const half8*)&Xl[nt * 16 + (lane & 15)][cc * 32 + (lane >> 4) * 8];
                    acc[nt] = __builtin_amdgcn_mfma_f32_16x16x32_f16(wf, xf, acc[nt], 0, 0, 0);
                }
            }
#pragma unroll
            for (int r = 0; r < 4; r++) {
                float bias = bp[d0 + 16 * w + (lane >> 4) * 4 + r];
#pragma unroll
                for (int nt = 0; nt < 4; nt++) {
                    _Float16 hv = (_Float16)(acc[nt][r] + bias);
                    if (proj < 2) Ol[nt * 16 + (lane & 15)][16 * w + (lane >> 4) * 4 + r] = hv;
                    else          Ol[16 * w + (lane >> 4) * 4 + r][nt * 16 + (lane & 15)] = hv;
                }
            }
            __syncthreads();
            _Float16* dst;
            size_t stride;
            if (proj == 0)      { dst = Qh + ((size_t)bs * NTOK + n0) * CDIM + d0; stride = CDIM; }
            else if (proj == 1) { dst = Kh + ((size_t)bs * NTOK + n0) * CDIM + d0; stride = CDIM; }
            else                { dst = Vt + ((size_t)bs * CDIM + d0) * NTOK + n0; stride = NTOK; }
#pragma unroll
            for (int i = 0; i < 4; i++) {
                int id = t + 256 * i;
                int row = id >> 4, c4 = (id & 15) * 4;
                *(half4*)(dst + (size_t)row * stride + c4) = *(const half4*)&Ol[row][c4];
            }
        }
    }
}

// ---------------------------------------------------------------------------
// Kernel 2: flash attention v5.
// Block = 512 threads = 8 waves = 4 q-groups x 2 m-groups; 128 q-rows/block;
// grid 256 (1 block/CU, 2 waves/SIMD). KVBLK=64, K+V double-buffered 128KB,
// fragment-ordered LDS layout (every ds_read_b128 lane-linear -> conflict
// free; global_load_lds linear dest + permuted global source).
// Wave (qg,mg): 32 q-rows, 32-token m-slice; online (m,l,O) per wave;
// flash-decode merge across mg pairs at the end.
// ---------------------------------------------------------------------------
__global__ __launch_bounds__(512, 2) void flash_kernel(
    const _Float16* __restrict__ Qh, const _Float16* __restrict__ Kh,
    const _Float16* __restrict__ Vt, float* __restrict__ out)
{
    __shared__ __align__(16) char smem[131072];  // 2 x (K 32KB | V 32KB)

    const int t = threadIdx.x, lane = t & 63;
    const int w = t >> 6;                 // 0..7
    const int qg = w >> 1, mg = w & 1;
    const int l5 = lane & 31, hi = lane >> 5;
    const int bs = blockIdx.x & 7;        // XCD-affine (256 % 8 == 0)
    const int qt = blockIdx.x >> 3;       // 0..31
    const int n0 = qt * 128;
    const int s = bs & 1, b = bs >> 1;

    // Q B-frags: col n = n0 + qg*32 + l5, k(c) = cc*16 + hi*8 + j
    half8 qf[16];
    {
        const _Float16* qp = Qh + ((size_t)bs * NTOK + n0 + qg * 32 + l5) * CDIM + hi * 8;
#pragma unroll
        for (int cc = 0; cc < 16; cc++) qf[cc] = *(const half8*)(qp + cc * 16);
    }

    const int bsK = b * 2 + (s ^ 1);
    const uint4* const Ksrc = (const uint4*)(Kh + (size_t)bsK * NTOK * CDIM);
    const uint4* const Vsrc = (const uint4*)(Vt + (size_t)bs * CDIM * NTOK);

    float m_run = -1e30f, l_run = 0.f;
    f32x16 Oacc[8];
    const f32x16 FZ16 = {0,0,0,0,0,0,0,0,0,0,0,0,0,0,0,0};
#pragma unroll
    for (int ct = 0; ct < 8; ct++) Oacc[ct] = FZ16;

    // Fragment-ordered staging. K chunk g<2048: instr=g>>6 (cc=instr>>1,
    // mt=instr&1); V chunk: instr=(g-2048)>>6 (kcg=instr>>3, ct=instr&7).
    // Lane fields of g are (hi,l5) = the reading lane. Dest = base + g*16.
    auto stage = [&](int buf, int kt) {
        const int m0 = kt * 64;
        char* base = smem + buf * 65536;
        if (w < 4) {
#pragma unroll
            for (int i = 0; i < 8; i++) {
                int instr = w * 8 + i;                 // 0..31
                int cc = instr >> 1, mt = instr & 1;
                GLD_LDS16(Ksrc + (size_t)(m0 + mt * 32 + l5) * 32 + cc * 2 + hi,
                          base + (instr * 64) * 16 + (hi * 32 + l5) * 16);
            }
        } else {
#pragma unroll
            for (int i = 0; i < 8; i++) {
                int instr = (w - 4) * 8 + i;           // 0..31
                int kcg = instr >> 3, ct = instr & 7;
                GLD_LDS16(Vsrc + (size_t)(ct * 32 + l5) * 512 + (m0 >> 3) + kcg * 2 + hi,
                          base + 32768 + (instr * 64) * 16 + (hi * 32 + l5) * 16);
            }
        }
    };

    stage(0, 0);
    __syncthreads();

    for (int kt = 0; kt < 64; kt++) {
        const int cur = kt & 1;
        if (kt < 63) stage(cur ^ 1, kt + 1);
        const char* Kb = smem + cur * 65536;
        const char* Vbuf = Kb + 32768;

        // ---- S^T slice = K(mg) Q^T : rows m = mg*32 tokens, cols = 32 q
        f32x16 sf = FZ16;
#pragma unroll
        for (int cc = 0; cc < 16; cc++) {
            half8 kf = *(const half8*)(Kb + (cc * 2 + mg) * 1024 + hi * 512 + l5 * 16);
            sf = __builtin_amdgcn_mfma_f32_32x32x16_f16(kf, qf[cc], sf, 0, 0, 0);
        }

        // ---- online softmax over this wave's 32-token slice (row q = l5)
        float pm = sf[0];
#pragma unroll
        for (int r = 1; r < 16; r++) pm = fmaxf(pm, sf[r]);
        pm = fmaxf(pm, __shfl_xor(pm, 32));

        if (__any(pm > m_run + 8.0f)) {        // defer-max
            float nm = fmaxf(m_run, pm);
            float sc = __expf(m_run - nm);
            m_run = nm;
            l_run *= sc;
#pragma unroll
            for (int reg = 0; reg < 16; reg++) {
                float sr = __shfl(sc, (reg & 3) + 8 * (reg >> 2) + 4 * hi);
#pragma unroll
                for (int ct = 0; ct < 8; ct++) Oacc[ct][reg] *= sr;
            }
        }

        float lsum = 0.f;
#pragma unroll
        for (int r = 0; r < 16; r++) {
            float p = __expf(sf[r] - m_run);
            sf[r] = p;
            lsum += p;
        }
        lsum += __shfl_xor(lsum, 32);
        l_run += lsum;

        // ---- P -> A-frags: 8 cvt_pk + 4 permlane32_swap (verified direction)
        uint4 paw[2];
#pragma unroll
        for (int kc = 0; kc < 2; kc++) {
            const int qe = kc * 8;
            unsigned A01 = pk16(sf[qe + 0], sf[qe + 1]);
            unsigned A23 = pk16(sf[qe + 2], sf[qe + 3]);
            unsigned B01 = pk16(sf[qe + 4], sf[qe + 5]);
            unsigned B23 = pk16(sf[qe + 6], sf[qe + 7]);
            unsigned d0 = A01, s0 = B01;
            asm volatile("v_permlane32_swap_b32 %0, %1" : "+v"(d0), "+v"(s0));
            unsigned d1 = A23, s1 = B23;
            asm volatile("v_permlane32_swap_b32 %0, %1" : "+v"(d1), "+v"(s1));
            paw[kc].x = d0; paw[kc].y = d1; paw[kc].z = s0; paw[kc].w = s1;
        }

        // ---- O += P(slice) V(slice)
#pragma unroll
        for (int kc = 0; kc < 2; kc++) {
            half8 pa;
            __builtin_memcpy(&pa, &paw[kc], 16);
            const int kcg = mg * 2 + kc;
#pragma unroll
            for (int ct = 0; ct < 8; ct++) {
                half8 vf = *(const half8*)(Vbuf + ((kcg * 8 + ct) * 64) * 16
                                                 + (hi * 32 + l5) * 16);
                Oacc[ct] = __builtin_amdgcn_mfma_f32_32x32x16_f16(pa, vf, Oacc[ct], 0, 0, 0);
            }
        }

        __syncthreads();   // compute done on cur; prefetch into cur^1 drained
    }

    // ================= mg-pair merge (flash-decode combine) =================
    // Obuf layout: [qg][ct(4)][rc(4)][lane][4 f32]  (lane-linear, 64KB)
    // mlbuf at +65536: [qg][l5] {m,l}
    float* const mlbuf = (float*)(smem + 65536);

    if (mg == 1 && hi == 0) {
        *(float2*)(mlbuf + (qg * 32 + l5) * 2) = make_float2(m_run, l_run);
    }
    // half 1: ct 0..3
    if (mg == 1) {
#pragma unroll
        for (int ct = 0; ct < 4; ct++)
#pragma unroll
            for (int rc = 0; rc < 4; rc++) {
                f32x4 v = { Oacc[ct][rc*4+0], Oacc[ct][rc*4+1], Oacc[ct][rc*4+2], Oacc[ct][rc*4+3] };
                *(f32x4*)(smem + ((qg * 4 + ct) * 4 + rc) * 1024 + lane * 16) = v;
            }
    }
    __syncthreads();

    float a_s = 0.f, b_s = 0.f;
    if (mg == 0) {
        float2 ml = *(const float2*)(mlbuf + (qg * 32 + l5) * 2);
        float mstar = fmaxf(m_run, ml.x);
        float e0 = __expf(m_run - mstar), e1 = __expf(ml.x - mstar);
        float ltot = l_run * e0 + ml.y * e1;
        a_s = e0 / ltot; b_s = e1 / ltot;
#pragma unroll
        for (int ct = 0; ct < 4; ct++)
#pragma unroll
            for (int rc = 0; rc < 4; rc++) {
                f32x4 o1 = *(const f32x4*)(smem + ((qg * 4 + ct) * 4 + rc) * 1024 + lane * 16);
#pragma unroll
                for (int j = 0; j < 4; j++) {
                    int r = j + 8 * rc + 4 * hi;
                    Oacc[ct][rc*4+j] = Oacc[ct][rc*4+j] * __shfl(a_s, r) + o1[j] * __shfl(b_s, r);
                }
            }
    }
    __syncthreads();
    // half 2: ct 4..7
    if (mg == 1) {
#pragma unroll
        for (int ct = 0; ct < 4; ct++)
#pragma unroll
            for (int rc = 0; rc < 4; rc++) {
                f32x4 v = { Oacc[ct+4][rc*4+0], Oacc[ct+4][rc*4+1], Oacc[ct+4][rc*4+2], Oacc[ct+4][rc*4+3] };
                *(f32x4*)(smem + ((qg * 4 + ct) * 4 + rc) * 1024 + lane * 16) = v;
            }
    }
    __syncthreads();
    if (mg == 0) {
#pragma unroll
        for (int ct = 0; ct < 4; ct++)
#pragma unroll
            for (int rc = 0; rc < 4; rc++) {
                f32x4 o1 = *(const f32x4*)(smem + ((qg * 4 + ct) * 4 + rc) * 1024 + lane * 16);
#pragma unroll
                for (int j = 0; j < 4; j++) {
                    int r = j + 8 * rc + 4 * hi;
                    Oacc[ct+4][rc*4+j] = Oacc[ct+4][rc*4+j] * __shfl(a_s, r) + o1[j] * __shfl(b_s, r);
                }
            }
    }

    // ---- epilogue: transpose via LDS (2 halves), coalesced [c][n] stores.
    // Only mg==0 waves hold merged O; all threads do the copy-out.
    float* obase = out + (size_t)(s * 4 + b) * CDIM * NTOK + n0;
    char* const Olp = smem;   // [128 c][128 n] f32, n-chunk ^= (c&7)
#pragma unroll
    for (int h = 0; h < 2; h++) {
        __syncthreads();
        if (mg == 0) {
#pragma unroll
            for (int ct4 = 0; ct4 < 4; ct4++) {
                int ct = h * 4 + ct4;
                int cl = ct4 * 32 + l5;
#pragma unroll
                for (int reg = 0; reg < 16; reg++) {
                    int n = qg * 32 + (reg & 3) + 8 * (reg >> 2) + 4 * hi;
                    int byteoff = cl * 512 + n * 4;
                    *(float*)(Olp + (byteoff ^ ((cl & 7) << 4))) = Oacc[ct][reg];
                }
            }
        }
        __syncthreads();
#pragma unroll
        for (int i = 0; i < 8; i++) {
            int id = t + 512 * i;
            int c = id >> 5, nc = id & 31;
            f32x4 v = *(const f32x4*)(Olp + c * 512 + ((nc ^ (c & 7)) << 4));
            *(f32x4*)(obase + (size_t)(h * 128 + c) * NTOK + nc * 4) = v;
        }
    }
}

// ---------------------------------------------------------------------------
extern "C" void kernel_launch(void* const* d_in, const int* in_sizes, int n_in,
                              void* d_out, int out_size, void* d_ws, size_t ws_size,
                              hipStream_t stream) {
    const float* x1 = (const float*)d_in[0];
    const float* x2 = (const float*)d_in[1];
    const float* Wq = (const float*)d_in[2];
    const float* bq = (const float*)d_in[3];
    const float* Wk = (const float*)d_in[4];
    const float* bk = (const float*)d_in[5];
    const float* Wv = (const float*)d_in[6];
    const float* bv = (const float*)d_in[7];

    _Float16* Qh = (_Float16*)d_ws;
    _Float16* Kh = Qh + (size_t)8 * NTOK * CDIM;
    _Float16* Vt = Kh + (size_t)8 * NTOK * CDIM;

    proj_kernel<<<dim3(512), dim3(256), 0, stream>>>(x1, x2, Wq, bq, Wk, bk, Wv, bv, Qh, Kh, Vt);
    flash_kernel<<<dim3(256), dim3(512), 0, stream>>>(Qh, Kh, Vt, (float*)d_out);
}